// Round 2
// baseline (89.781 us; speedup 1.0000x reference)
//
#include <hip/hip_runtime.h>
#include <hip/hip_bf16.h>

typedef __bf16 bf16x8 __attribute__((ext_vector_type(8)));
typedef float f32x4 __attribute__((ext_vector_type(4)));

#define BN_EPS 1e-5f
#define RB 4   // rows per wave iteration (MLP batching)

// One wave processes RB rows per iteration. Per row:
//   A-frag (k-tile kt): lane l holds G[kt*16 + (l&15)][8*(l>>4)+j]  (one 32B gather chunk)
//   B-frag (o-tile t):  lane l holds W[t*16 + (l&15)][8*(l>>4)+j]
//   D: lane l, reg q = proj[kt*16 + (l>>4)*4 + q][t*16 + (l&15)]
// All RB*4 gather loads are issued before any consumption; next batch's
// idx/mask loads are issued under the current batch's convert/MFMA/store.
__global__ __launch_bounds__(256, 4) void down_kernel(
    const float* __restrict__ vf,     // [N,32]
    const int*   __restrict__ kidx,   // [M,32]
    const int*   __restrict__ kmask,  // [M,32] (1 = invalid)
    const float* __restrict__ W,      // [64,32]
    const float* __restrict__ bias,
    const float* __restrict__ gamma,
    const float* __restrict__ beta,
    const float* __restrict__ mean,
    const float* __restrict__ var,
    float* __restrict__ out,          // [M,64]
    int M)
{
    const int lane = threadIdx.x & 63;
    const int col  = lane & 15;
    const int grp  = lane >> 4;
    const int c0   = grp << 3;

    const int waves_per_block = blockDim.x >> 6;
    const int wave_id     = blockIdx.x * waves_per_block + (threadIdx.x >> 6);
    const int total_waves = gridDim.x * waves_per_block;

    // ---- loop-invariant: B fragments + folded BN affine ----
    bf16x8 bfrag[4];
    float S[4], T[4];
#pragma unroll
    for (int t = 0; t < 4; ++t) {
        const int o = t * 16 + col;
        const f32x4 w0 = *(const f32x4*)(W + o * 32 + c0);
        const f32x4 w1 = *(const f32x4*)(W + o * 32 + c0 + 4);
        bf16x8 f;
        f[0]=(__bf16)w0.x; f[1]=(__bf16)w0.y; f[2]=(__bf16)w0.z; f[3]=(__bf16)w0.w;
        f[4]=(__bf16)w1.x; f[5]=(__bf16)w1.y; f[6]=(__bf16)w1.z; f[7]=(__bf16)w1.w;
        bfrag[t] = f;
        const float s = gamma[o] * rsqrtf(var[o] + BN_EPS);
        S[t] = s;
        T[t] = (bias[o] - mean[o]) * s + beta[o];
    }

    const f32x4 zero4 = {0.f, 0.f, 0.f, 0.f};
    const int stride = total_waves * RB;

    int m0 = wave_id * RB;
    if (m0 >= M) return;

    // ---- prologue: idx/mask for first batch ----
    int id[RB][2], mk[RB][2];
#pragma unroll
    for (int r = 0; r < RB; ++r) {
        int m = m0 + r; m = m < M ? m : M - 1;
        const int* ip = kidx  + (size_t)m * 32;
        const int* mp = kmask + (size_t)m * 32;
        id[r][0] = ip[col];  id[r][1] = ip[col + 16];
        mk[r][0] = mp[col];  mk[r][1] = mp[col + 16];
    }

    while (true) {
        const int nm0 = m0 + stride;
        const int pm0 = nm0 < M ? nm0 : 0;   // clamped prefetch base (data discarded on exit)

        // ---- phase 1: issue ALL gathers for this batch (16 dwordx4 in flight) ----
        f32x4 g[RB][2][2];
#pragma unroll
        for (int r = 0; r < RB; ++r) {
#pragma unroll
            for (int kt = 0; kt < 2; ++kt) {
                int i = id[r][kt]; i = i < 0 ? 0 : i;
                const float* src = vf + (size_t)i * 32 + c0;
                g[r][kt][0] = *(const f32x4*)(src);
                g[r][kt][1] = *(const f32x4*)(src + 4);
            }
        }

        // ---- phase 2: prefetch next batch's idx/mask under the gathers ----
        int nid[RB][2], nmk[RB][2];
#pragma unroll
        for (int r = 0; r < RB; ++r) {
            int m = pm0 + r; m = m < M ? m : M - 1;
            const int* ip = kidx  + (size_t)m * 32;
            const int* mp = kmask + (size_t)m * 32;
            nid[r][0] = ip[col];  nid[r][1] = ip[col + 16];
            nmk[r][0] = mp[col];  nmk[r][1] = mp[col + 16];
        }

        // ---- phase 3: per-row convert + MFMA + fused BN/ReLU/max + store ----
#pragma unroll
        for (int r = 0; r < RB; ++r) {
            const int m = m0 + r;
            bf16x8 afrag[2];
#pragma unroll
            for (int kt = 0; kt < 2; ++kt) {
                const float sel = (mk[r][kt] == 0) ? 1.0f : 0.0f;
                const f32x4 g0 = g[r][kt][0], g1 = g[r][kt][1];
                bf16x8 a;
                a[0]=(__bf16)(g0.x*sel); a[1]=(__bf16)(g0.y*sel);
                a[2]=(__bf16)(g0.z*sel); a[3]=(__bf16)(g0.w*sel);
                a[4]=(__bf16)(g1.x*sel); a[5]=(__bf16)(g1.y*sel);
                a[6]=(__bf16)(g1.z*sel); a[7]=(__bf16)(g1.w*sel);
                afrag[kt] = a;
            }
            float myout = 0.0f;
#pragma unroll
            for (int t = 0; t < 4; ++t) {
                f32x4 d0 = __builtin_amdgcn_mfma_f32_16x16x32_bf16(afrag[0], bfrag[t], zero4, 0, 0, 0);
                f32x4 d1 = __builtin_amdgcn_mfma_f32_16x16x32_bf16(afrag[1], bfrag[t], zero4, 0, 0, 0);
                float v = 0.0f;   // ReLU folded into max
#pragma unroll
                for (int q = 0; q < 4; ++q) {
                    v = fmaxf(v, d0[q] * S[t] + T[t]);
                    v = fmaxf(v, d1[q] * S[t] + T[t]);
                }
                v = fmaxf(v, __shfl_xor(v, 16));
                v = fmaxf(v, __shfl_xor(v, 32));
                if (grp == t) myout = v;
            }
            if (m < M) out[(size_t)m * 64 + lane] = myout;
        }

        if (nm0 >= M) break;
        m0 = nm0;
#pragma unroll
        for (int r = 0; r < RB; ++r) {
            id[r][0] = nid[r][0]; id[r][1] = nid[r][1];
            mk[r][0] = nmk[r][0]; mk[r][1] = nmk[r][1];
        }
    }
}

extern "C" void kernel_launch(void* const* d_in, const int* in_sizes, int n_in,
                              void* d_out, int out_size, void* d_ws, size_t ws_size,
                              hipStream_t stream) {
    const float* vf    = (const float*)d_in[0];
    const int*   kidx  = (const int*)  d_in[1];
    const int*   kmask = (const int*)  d_in[2];
    const float* W     = (const float*)d_in[3];
    const float* bias  = (const float*)d_in[4];
    const float* gamma = (const float*)d_in[5];
    const float* beta  = (const float*)d_in[6];
    const float* mean  = (const float*)d_in[7];
    const float* var   = (const float*)d_in[8];
    float* out = (float*)d_out;

    const int M = in_sizes[1] / 32;   // key_indices is [M,32]

    down_kernel<<<2048, 256, 0, stream>>>(vf, kidx, kmask, W, bias, gamma,
                                          beta, mean, var, out, M);
}

// Round 3
// 75.916 us; speedup vs baseline: 1.1826x; 1.1826x over previous
//
#include <hip/hip_runtime.h>
#include <hip/hip_bf16.h>

typedef __bf16 bf16x8 __attribute__((ext_vector_type(8)));
typedef float f32x4 __attribute__((ext_vector_type(4)));
typedef unsigned int u32;
typedef u32 u32x4 __attribute__((ext_vector_type(4)));

#define BN_EPS 1e-5f
#define RB 4   // rows per wave iteration

// ---------- prepass: fp32 table -> bf16 table (in d_ws) ----------
__global__ __launch_bounds__(256) void convert_kernel(
    const float* __restrict__ vf, __bf16* __restrict__ tb, int n8)
{
    int i = blockIdx.x * blockDim.x + threadIdx.x;
    const int stride = gridDim.x * blockDim.x;
    for (; i < n8; i += stride) {
        const f32x4 a = ((const f32x4*)vf)[2 * i];
        const f32x4 b = ((const f32x4*)vf)[2 * i + 1];
        bf16x8 o;
        o[0]=(__bf16)a.x; o[1]=(__bf16)a.y; o[2]=(__bf16)a.z; o[3]=(__bf16)a.w;
        o[4]=(__bf16)b.x; o[5]=(__bf16)b.y; o[6]=(__bf16)b.z; o[7]=(__bf16)b.w;
        ((bf16x8*)tb)[i] = o;
    }
}

// ---------- main: gather(bf16) -> MFMA -> BN/ReLU/max ----------
//   A-frag (row r, k-tile kt): lane l holds T[idx[r][kt*16+(l&15)]][8*(l>>4)+j]
//                              = ONE dwordx4 gather per (row, kt)
//   B-frag (o-tile t): lane l holds W[t*16+(l&15)][8*(l>>4)+j]
//   D: lane l, reg q = proj[kt*16 + (l>>4)*4 + q][t*16 + (l&15)]
__global__ __launch_bounds__(256, 4) void down_bf16(
    const __bf16* __restrict__ tb,    // [N,32] bf16 table
    const int*   __restrict__ kidx,   // [M,32]
    const int*   __restrict__ kmask,  // [M,32] (1 = invalid)
    const float* __restrict__ W,      // [64,32]
    const float* __restrict__ bias,
    const float* __restrict__ gamma,
    const float* __restrict__ beta,
    const float* __restrict__ mean,
    const float* __restrict__ var,
    float* __restrict__ out,          // [M,64]
    int M)
{
    const int lane = threadIdx.x & 63;
    const int col  = lane & 15;
    const int grp  = lane >> 4;
    const int c0   = grp << 3;

    const int waves_per_block = blockDim.x >> 6;
    const int wave_id     = blockIdx.x * waves_per_block + (threadIdx.x >> 6);
    const int total_waves = gridDim.x * waves_per_block;

    // loop-invariant: B fragments + folded BN affine
    bf16x8 bfrag[4];
    float S[4], T[4];
#pragma unroll
    for (int t = 0; t < 4; ++t) {
        const int o = t * 16 + col;
        const f32x4 w0 = *(const f32x4*)(W + o * 32 + c0);
        const f32x4 w1 = *(const f32x4*)(W + o * 32 + c0 + 4);
        bf16x8 f;
        f[0]=(__bf16)w0.x; f[1]=(__bf16)w0.y; f[2]=(__bf16)w0.z; f[3]=(__bf16)w0.w;
        f[4]=(__bf16)w1.x; f[5]=(__bf16)w1.y; f[6]=(__bf16)w1.z; f[7]=(__bf16)w1.w;
        bfrag[t] = f;
        const float s = gamma[o] * rsqrtf(var[o] + BN_EPS);
        S[t] = s;
        T[t] = (bias[o] - mean[o]) * s + beta[o];
    }

    const f32x4 zero4 = {0.f, 0.f, 0.f, 0.f};
    const u32x4 zu4   = {0u, 0u, 0u, 0u};
    const int stride = total_waves * RB;

    for (int m0 = wave_id * RB; m0 < M; m0 += stride) {
        // phase 1: idx/mask for RB rows (clamped; tail rows recompute row M-1)
        int id[RB][2], mk[RB][2];
#pragma unroll
        for (int r = 0; r < RB; ++r) {
            int m = m0 + r; m = m < M ? m : M - 1;
            const int* ip = kidx  + (size_t)m * 32;
            const int* mp = kmask + (size_t)m * 32;
            id[r][0] = __builtin_nontemporal_load(ip + col);
            id[r][1] = __builtin_nontemporal_load(ip + col + 16);
            mk[r][0] = __builtin_nontemporal_load(mp + col);
            mk[r][1] = __builtin_nontemporal_load(mp + col + 16);
        }

        // phase 2: issue ALL RB*2 gathers (one dwordx4 each) before any use
        u32x4 g[RB][2];
#pragma unroll
        for (int r = 0; r < RB; ++r) {
#pragma unroll
            for (int kt = 0; kt < 2; ++kt) {
                int i = id[r][kt]; i = i < 0 ? 0 : i;
                g[r][kt] = *(const u32x4*)(tb + (size_t)i * 32 + c0);
            }
        }

        // phase 3: mask, MFMA, fused BN/ReLU/max, store
#pragma unroll
        for (int r = 0; r < RB; ++r) {
            const int m = m0 + r;
            bf16x8 afrag[2];
#pragma unroll
            for (int kt = 0; kt < 2; ++kt) {
                const u32x4 gv = (mk[r][kt] == 0) ? g[r][kt] : zu4;
                afrag[kt] = __builtin_bit_cast(bf16x8, gv);
            }
            float myout = 0.0f;
#pragma unroll
            for (int t = 0; t < 4; ++t) {
                f32x4 d0 = __builtin_amdgcn_mfma_f32_16x16x32_bf16(afrag[0], bfrag[t], zero4, 0, 0, 0);
                f32x4 d1 = __builtin_amdgcn_mfma_f32_16x16x32_bf16(afrag[1], bfrag[t], zero4, 0, 0, 0);
                float v = 0.0f;   // ReLU folded into max
#pragma unroll
                for (int q = 0; q < 4; ++q) {
                    v = fmaxf(v, d0[q] * S[t] + T[t]);
                    v = fmaxf(v, d1[q] * S[t] + T[t]);
                }
                v = fmaxf(v, __shfl_xor(v, 16));
                v = fmaxf(v, __shfl_xor(v, 32));
                if (grp == t) myout = v;
            }
            if (m < M) __builtin_nontemporal_store(myout, out + (size_t)m * 64 + lane);
        }
    }
}

// ---------- fallback (fp32 gather, R0 structure) if ws too small ----------
__global__ __launch_bounds__(256, 4) void down_fp32(
    const float* __restrict__ vf, const int* __restrict__ kidx,
    const int* __restrict__ kmask, const float* __restrict__ W,
    const float* __restrict__ bias, const float* __restrict__ gamma,
    const float* __restrict__ beta, const float* __restrict__ mean,
    const float* __restrict__ var, float* __restrict__ out, int M)
{
    const int lane = threadIdx.x & 63;
    const int col  = lane & 15;
    const int grp  = lane >> 4;
    const int c0   = grp << 3;
    const int waves_per_block = blockDim.x >> 6;
    const int wave_id     = blockIdx.x * waves_per_block + (threadIdx.x >> 6);
    const int total_waves = gridDim.x * waves_per_block;

    bf16x8 bfrag[4];
    float S[4], T[4];
#pragma unroll
    for (int t = 0; t < 4; ++t) {
        const int o = t * 16 + col;
        const f32x4 w0 = *(const f32x4*)(W + o * 32 + c0);
        const f32x4 w1 = *(const f32x4*)(W + o * 32 + c0 + 4);
        bf16x8 f;
        f[0]=(__bf16)w0.x; f[1]=(__bf16)w0.y; f[2]=(__bf16)w0.z; f[3]=(__bf16)w0.w;
        f[4]=(__bf16)w1.x; f[5]=(__bf16)w1.y; f[6]=(__bf16)w1.z; f[7]=(__bf16)w1.w;
        bfrag[t] = f;
        const float s = gamma[o] * rsqrtf(var[o] + BN_EPS);
        S[t] = s;
        T[t] = (bias[o] - mean[o]) * s + beta[o];
    }
    const f32x4 zero4 = {0.f, 0.f, 0.f, 0.f};
    for (int m = wave_id; m < M; m += total_waves) {
        const int* idxp = kidx  + (size_t)m * 32;
        const int* mskp = kmask + (size_t)m * 32;
        bf16x8 afrag[2];
#pragma unroll
        for (int kt = 0; kt < 2; ++kt) {
            const int k = kt * 16 + col;
            int id = idxp[k]; id = id < 0 ? 0 : id;
            const float sel = (mskp[k] == 0) ? 1.0f : 0.0f;
            const float* src = vf + (size_t)id * 32 + c0;
            const f32x4 g0 = *(const f32x4*)(src);
            const f32x4 g1 = *(const f32x4*)(src + 4);
            bf16x8 a;
            a[0]=(__bf16)(g0.x*sel); a[1]=(__bf16)(g0.y*sel);
            a[2]=(__bf16)(g0.z*sel); a[3]=(__bf16)(g0.w*sel);
            a[4]=(__bf16)(g1.x*sel); a[5]=(__bf16)(g1.y*sel);
            a[6]=(__bf16)(g1.z*sel); a[7]=(__bf16)(g1.w*sel);
            afrag[kt] = a;
        }
        float myout = 0.0f;
#pragma unroll
        for (int t = 0; t < 4; ++t) {
            f32x4 d0 = __builtin_amdgcn_mfma_f32_16x16x32_bf16(afrag[0], bfrag[t], zero4, 0, 0, 0);
            f32x4 d1 = __builtin_amdgcn_mfma_f32_16x16x32_bf16(afrag[1], bfrag[t], zero4, 0, 0, 0);
            float v = 0.0f;
#pragma unroll
            for (int q = 0; q < 4; ++q) {
                v = fmaxf(v, d0[q] * S[t] + T[t]);
                v = fmaxf(v, d1[q] * S[t] + T[t]);
            }
            v = fmaxf(v, __shfl_xor(v, 16));
            v = fmaxf(v, __shfl_xor(v, 32));
            if (grp == t) myout = v;
        }
        out[(size_t)m * 64 + lane] = myout;
    }
}

extern "C" void kernel_launch(void* const* d_in, const int* in_sizes, int n_in,
                              void* d_out, int out_size, void* d_ws, size_t ws_size,
                              hipStream_t stream) {
    const float* vf    = (const float*)d_in[0];
    const int*   kidx  = (const int*)  d_in[1];
    const int*   kmask = (const int*)  d_in[2];
    const float* W     = (const float*)d_in[3];
    const float* bias  = (const float*)d_in[4];
    const float* gamma = (const float*)d_in[5];
    const float* beta  = (const float*)d_in[6];
    const float* mean  = (const float*)d_in[7];
    const float* var   = (const float*)d_in[8];
    float* out = (float*)d_out;

    const int NC = in_sizes[0];        // N*32 floats
    const int M  = in_sizes[1] / 32;   // key_indices is [M,32]
    const size_t need = (size_t)NC * sizeof(__bf16);

    if (ws_size >= need) {
        __bf16* tb = (__bf16*)d_ws;
        convert_kernel<<<2048, 256, 0, stream>>>(vf, tb, NC / 8);
        down_bf16<<<2048, 256, 0, stream>>>(tb, kidx, kmask, W, bias, gamma,
                                            beta, mean, var, out, M);
    } else {
        down_fp32<<<2048, 256, 0, stream>>>(vf, kidx, kmask, W, bias, gamma,
                                            beta, mean, var, out, M);
    }
}

// Round 4
// 62.328 us; speedup vs baseline: 1.4405x; 1.2180x over previous
//
#include <hip/hip_runtime.h>
#include <hip/hip_bf16.h>

typedef __bf16 bf16x8 __attribute__((ext_vector_type(8)));
typedef float f32x4 __attribute__((ext_vector_type(4)));
typedef unsigned int u32;
typedef u32 u32x4 __attribute__((ext_vector_type(4)));

#define BN_EPS 1e-5f
#define RB 4   // rows per wave (one-shot, no loop)

// ---------- prepass: fp32 table -> bf16 table (in d_ws), + zero row at [N] ----------
__global__ __launch_bounds__(256) void convert_kernel(
    const float* __restrict__ vf, __bf16* __restrict__ tb, int n8, int N)
{
    if (blockIdx.x == 0 && threadIdx.x < 4) {
        // zero row at tb[N] — invalid neighbors gather from here
        bf16x8 z = {};
        ((bf16x8*)(tb + (size_t)N * 32))[threadIdx.x] = z;
    }
    int i = blockIdx.x * blockDim.x + threadIdx.x;
    const int stride = gridDim.x * blockDim.x;
    for (; i < n8; i += stride) {
        const f32x4 a = ((const f32x4*)vf)[2 * i];
        const f32x4 b = ((const f32x4*)vf)[2 * i + 1];
        bf16x8 o;
        o[0]=(__bf16)a.x; o[1]=(__bf16)a.y; o[2]=(__bf16)a.z; o[3]=(__bf16)a.w;
        o[4]=(__bf16)b.x; o[5]=(__bf16)b.y; o[6]=(__bf16)b.z; o[7]=(__bf16)b.w;
        ((bf16x8*)tb)[i] = o;
    }
}

// ---------- main: one-shot, wave = RB rows ----------
//   A-frag (row r, k-tile kt): lane l holds T[fid[r][kt*16+(l&15)]][8*(l>>4)+j]
//   B-frag (o-tile t): lane l holds W[t*16+(l&15)][8*(l>>4)+j]
//   D: lane l, reg q = proj[kt*16 + (l>>4)*4 + q][t*16 + (l&15)]
// Invalid neighbors point at zero row N -> no mask select in the hot path.
__global__ __launch_bounds__(256, 4) void down_bf16(
    const __bf16* __restrict__ tb,    // [N+1,32] bf16 table (row N = zeros)
    const int*   __restrict__ kidx,   // [M,32]
    const int*   __restrict__ kmask,  // [M,32] (1 = invalid)
    const float* __restrict__ W,      // [64,32]
    const float* __restrict__ bias,
    const float* __restrict__ gamma,
    const float* __restrict__ beta,
    const float* __restrict__ mean,
    const float* __restrict__ var,
    float* __restrict__ out,          // [M,64]
    int M, int N)
{
    const int lane = threadIdx.x & 63;
    const int col  = lane & 15;
    const int grp  = lane >> 4;
    const int c0   = grp << 3;

    const int waves_per_block = blockDim.x >> 6;
    const int wave_id = blockIdx.x * waves_per_block + (threadIdx.x >> 6);
    const int m0 = wave_id * RB;
    if (m0 >= M) return;

    // ---- phase 1: issue idx+mask loads for all RB rows immediately ----
    int id[RB][2], mk[RB][2];
#pragma unroll
    for (int r = 0; r < RB; ++r) {
        int m = m0 + r; m = m < M ? m : M - 1;
        const int* ip = kidx  + (size_t)m * 32;
        const int* mp = kmask + (size_t)m * 32;
        id[r][0] = __builtin_nontemporal_load(ip + col);
        id[r][1] = __builtin_nontemporal_load(ip + col + 16);
        mk[r][0] = __builtin_nontemporal_load(mp + col);
        mk[r][1] = __builtin_nontemporal_load(mp + col + 16);
    }

    // ---- loop-invariant under the idx-load shadow: B frags + BN affine ----
    bf16x8 bfrag[4];
    float S[4], T[4];
#pragma unroll
    for (int t = 0; t < 4; ++t) {
        const int o = t * 16 + col;
        const f32x4 w0 = *(const f32x4*)(W + o * 32 + c0);
        const f32x4 w1 = *(const f32x4*)(W + o * 32 + c0 + 4);
        bf16x8 f;
        f[0]=(__bf16)w0.x; f[1]=(__bf16)w0.y; f[2]=(__bf16)w0.z; f[3]=(__bf16)w0.w;
        f[4]=(__bf16)w1.x; f[5]=(__bf16)w1.y; f[6]=(__bf16)w1.z; f[7]=(__bf16)w1.w;
        bfrag[t] = f;
        const float s = gamma[o] * rsqrtf(var[o] + BN_EPS);
        S[t] = s;
        T[t] = (bias[o] - mean[o]) * s + beta[o];
    }

    // ---- phase 2: issue ALL RB*2 gathers (invalid -> zero row N) ----
    u32x4 g[RB][2];
#pragma unroll
    for (int r = 0; r < RB; ++r) {
#pragma unroll
        for (int kt = 0; kt < 2; ++kt) {
            int i = id[r][kt]; i = i < 0 ? 0 : i;
            i = (mk[r][kt] == 0) ? i : N;
            g[r][kt] = *(const u32x4*)(tb + (size_t)i * 32 + c0);
        }
    }

    // ---- phase 3: MFMA + fused BN/ReLU/max + store ----
    const f32x4 zero4 = {0.f, 0.f, 0.f, 0.f};
#pragma unroll
    for (int r = 0; r < RB; ++r) {
        const int m = m0 + r;
        const bf16x8 a0 = __builtin_bit_cast(bf16x8, g[r][0]);
        const bf16x8 a1 = __builtin_bit_cast(bf16x8, g[r][1]);
        float myout = 0.0f;
#pragma unroll
        for (int t = 0; t < 4; ++t) {
            f32x4 d0 = __builtin_amdgcn_mfma_f32_16x16x32_bf16(a0, bfrag[t], zero4, 0, 0, 0);
            f32x4 d1 = __builtin_amdgcn_mfma_f32_16x16x32_bf16(a1, bfrag[t], zero4, 0, 0, 0);
            float v = 0.0f;   // ReLU folded into max
#pragma unroll
            for (int q = 0; q < 4; ++q) {
                v = fmaxf(v, d0[q] * S[t] + T[t]);
                v = fmaxf(v, d1[q] * S[t] + T[t]);
            }
            v = fmaxf(v, __shfl_xor(v, 16));
            v = fmaxf(v, __shfl_xor(v, 32));
            if (grp == t) myout = v;
        }
        if (m < M) __builtin_nontemporal_store(myout, out + (size_t)m * 64 + lane);
    }
}

// ---------- fallback (fp32 gather, no workspace needed) ----------
__global__ __launch_bounds__(256, 4) void down_fp32(
    const float* __restrict__ vf, const int* __restrict__ kidx,
    const int* __restrict__ kmask, const float* __restrict__ W,
    const float* __restrict__ bias, const float* __restrict__ gamma,
    const float* __restrict__ beta, const float* __restrict__ mean,
    const float* __restrict__ var, float* __restrict__ out, int M)
{
    const int lane = threadIdx.x & 63;
    const int col  = lane & 15;
    const int grp  = lane >> 4;
    const int c0   = grp << 3;
    const int waves_per_block = blockDim.x >> 6;
    const int wave_id     = blockIdx.x * waves_per_block + (threadIdx.x >> 6);
    const int total_waves = gridDim.x * waves_per_block;

    bf16x8 bfrag[4];
    float S[4], T[4];
#pragma unroll
    for (int t = 0; t < 4; ++t) {
        const int o = t * 16 + col;
        const f32x4 w0 = *(const f32x4*)(W + o * 32 + c0);
        const f32x4 w1 = *(const f32x4*)(W + o * 32 + c0 + 4);
        bf16x8 f;
        f[0]=(__bf16)w0.x; f[1]=(__bf16)w0.y; f[2]=(__bf16)w0.z; f[3]=(__bf16)w0.w;
        f[4]=(__bf16)w1.x; f[5]=(__bf16)w1.y; f[6]=(__bf16)w1.z; f[7]=(__bf16)w1.w;
        bfrag[t] = f;
        const float s = gamma[o] * rsqrtf(var[o] + BN_EPS);
        S[t] = s;
        T[t] = (bias[o] - mean[o]) * s + beta[o];
    }
    const f32x4 zero4 = {0.f, 0.f, 0.f, 0.f};
    for (int m = wave_id; m < M; m += total_waves) {
        const int* idxp = kidx  + (size_t)m * 32;
        const int* mskp = kmask + (size_t)m * 32;
        bf16x8 afrag[2];
#pragma unroll
        for (int kt = 0; kt < 2; ++kt) {
            const int k = kt * 16 + col;
            int id = idxp[k]; id = id < 0 ? 0 : id;
            const float sel = (mskp[k] == 0) ? 1.0f : 0.0f;
            const float* src = vf + (size_t)id * 32 + c0;
            const f32x4 g0 = *(const f32x4*)(src);
            const f32x4 g1 = *(const f32x4*)(src + 4);
            bf16x8 a;
            a[0]=(__bf16)(g0.x*sel); a[1]=(__bf16)(g0.y*sel);
            a[2]=(__bf16)(g0.z*sel); a[3]=(__bf16)(g0.w*sel);
            a[4]=(__bf16)(g1.x*sel); a[5]=(__bf16)(g1.y*sel);
            a[6]=(__bf16)(g1.z*sel); a[7]=(__bf16)(g1.w*sel);
            afrag[kt] = a;
        }
        float myout = 0.0f;
#pragma unroll
        for (int t = 0; t < 4; ++t) {
            f32x4 d0 = __builtin_amdgcn_mfma_f32_16x16x32_bf16(afrag[0], bfrag[t], zero4, 0, 0, 0);
            f32x4 d1 = __builtin_amdgcn_mfma_f32_16x16x32_bf16(afrag[1], bfrag[t], zero4, 0, 0, 0);
            float v = 0.0f;
#pragma unroll
            for (int q = 0; q < 4; ++q) {
                v = fmaxf(v, d0[q] * S[t] + T[t]);
                v = fmaxf(v, d1[q] * S[t] + T[t]);
            }
            v = fmaxf(v, __shfl_xor(v, 16));
            v = fmaxf(v, __shfl_xor(v, 32));
            if (grp == t) myout = v;
        }
        out[(size_t)m * 64 + lane] = myout;
    }
}

extern "C" void kernel_launch(void* const* d_in, const int* in_sizes, int n_in,
                              void* d_out, int out_size, void* d_ws, size_t ws_size,
                              hipStream_t stream) {
    const float* vf    = (const float*)d_in[0];
    const int*   kidx  = (const int*)  d_in[1];
    const int*   kmask = (const int*)  d_in[2];
    const float* W     = (const float*)d_in[3];
    const float* bias  = (const float*)d_in[4];
    const float* gamma = (const float*)d_in[5];
    const float* beta  = (const float*)d_in[6];
    const float* mean  = (const float*)d_in[7];
    const float* var   = (const float*)d_in[8];
    float* out = (float*)d_out;

    const int NC = in_sizes[0];        // N*32 floats
    const int N  = NC / 32;
    const int M  = in_sizes[1] / 32;   // key_indices is [M,32]
    const size_t need = ((size_t)NC + 32) * sizeof(__bf16);  // +1 zero row

    if (ws_size >= need) {
        __bf16* tb = (__bf16*)d_ws;
        convert_kernel<<<2048, 256, 0, stream>>>(vf, tb, NC / 8, N);
        const int rows_per_block = (256 / 64) * RB;   // 16
        const int blocks = (M + rows_per_block - 1) / rows_per_block;
        down_bf16<<<blocks, 256, 0, stream>>>(tb, kidx, kmask, W, bias, gamma,
                                              beta, mean, var, out, M, N);
    } else {
        down_fp32<<<2048, 256, 0, stream>>>(vf, kidx, kmask, W, bias, gamma,
                                            beta, mean, var, out, M);
    }
}

// Round 5
// 58.228 us; speedup vs baseline: 1.5419x; 1.0704x over previous
//
#include <hip/hip_runtime.h>
#include <hip/hip_bf16.h>

typedef __bf16 bf16x8 __attribute__((ext_vector_type(8)));
typedef float f32x4 __attribute__((ext_vector_type(4)));
typedef unsigned int u32;
typedef u32 u32x4 __attribute__((ext_vector_type(4)));

#define BN_EPS 1e-5f
#define RB 8   // rows per wave (one-shot)

// ---------------- prepass 1: fp32 table -> bf16 table ----------------
__global__ __launch_bounds__(256) void convert_kernel(
    const float* __restrict__ vf, __bf16* __restrict__ tb, int n8)
{
    int i = blockIdx.x * blockDim.x + threadIdx.x;
    const int stride = gridDim.x * blockDim.x;
    for (; i < n8; i += stride) {
        const f32x4 a = ((const f32x4*)vf)[2 * i];
        const f32x4 b = ((const f32x4*)vf)[2 * i + 1];
        bf16x8 o;
        o[0]=(__bf16)a.x; o[1]=(__bf16)a.y; o[2]=(__bf16)a.z; o[3]=(__bf16)a.w;
        o[4]=(__bf16)b.x; o[5]=(__bf16)b.y; o[6]=(__bf16)b.z; o[7]=(__bf16)b.w;
        ((bf16x8*)tb)[i] = o;
    }
}

// ---------------- prepass 2: pack W-frags + BN affine + zero row ----------------
// packB[t*64 + lane] = bf16x8 of W[t*16+(lane&15)][8*(lane>>4) .. +7]
// SP[lane] = {S[o(t=0..3)]}, TP[lane] = {T[...]}, o = t*16 + (lane&15)
__global__ __launch_bounds__(64) void pack_kernel(
    const float* __restrict__ W, const float* __restrict__ bias,
    const float* __restrict__ gamma, const float* __restrict__ beta,
    const float* __restrict__ mean, const float* __restrict__ var,
    __bf16* __restrict__ tb, u32* __restrict__ packB,
    float* __restrict__ SP, float* __restrict__ TP, int N)
{
    const int lane = threadIdx.x;
    const int col = lane & 15, grp = lane >> 4, c0 = grp << 3;
    if (lane < 16) ((u32*)(tb + (size_t)N * 32))[lane] = 0u;   // zero row
    f32x4 s4, t4;
#pragma unroll
    for (int t = 0; t < 4; ++t) {
        const int o = t * 16 + col;
        const f32x4 w0 = *(const f32x4*)(W + o * 32 + c0);
        const f32x4 w1 = *(const f32x4*)(W + o * 32 + c0 + 4);
        bf16x8 f;
        f[0]=(__bf16)w0.x; f[1]=(__bf16)w0.y; f[2]=(__bf16)w0.z; f[3]=(__bf16)w0.w;
        f[4]=(__bf16)w1.x; f[5]=(__bf16)w1.y; f[6]=(__bf16)w1.z; f[7]=(__bf16)w1.w;
        ((bf16x8*)packB)[t * 64 + lane] = f;
        const float s = gamma[o] * rsqrtf(var[o] + BN_EPS);
        s4[t] = s;
        t4[t] = (bias[o] - mean[o]) * s + beta[o];
    }
    ((f32x4*)SP)[lane] = s4;
    ((f32x4*)TP)[lane] = t4;
}

// ---------------- main: one-shot, wave = 8 rows ----------------
//   idx/mask: 8 fully-coalesced dword loads -> ds_bpermute redistribution
//   A-frag (row r, kt): lane l holds T[fid[r][kt]][8*(l>>4)+j] (one dwordx4 gather)
//   invalid neighbors -> zero row N
__global__ __launch_bounds__(256, 4) void down_bf16(
    const __bf16* __restrict__ tb,    // [N+1,32] bf16 (row N = zeros)
    const int*   __restrict__ kidx,   // [M,32]
    const int*   __restrict__ kmask,  // [M,32] (1 = invalid)
    const u32*   __restrict__ packB,  // packed W frags
    const float* __restrict__ SP,     // per-lane S x4
    const float* __restrict__ TP,     // per-lane T x4
    float* __restrict__ out,          // [M,64]
    int M, int N)
{
    const int lane = threadIdx.x & 63;
    const int col  = lane & 15;
    const int grp  = lane >> 4;
    const int c0   = grp << 3;

    const int wave_id = blockIdx.x * (blockDim.x >> 6) + (threadIdx.x >> 6);
    const int m0 = wave_id * RB;
    if (m0 >= M) return;

    // ---- A: coalesced idx+mask loads (8 loads, all 64 lanes useful) ----
    const int elim  = M * 32 - 1;
    const int ebase = m0 * 32 + lane;
    int ci[4], cm[4];
#pragma unroll
    for (int i = 0; i < 4; ++i) {
        int e = ebase + i * 64; e = e < elim ? e : elim;
        ci[i] = __builtin_nontemporal_load(kidx + e);
    }
#pragma unroll
    for (int i = 0; i < 4; ++i) {
        int e = ebase + i * 64; e = e < elim ? e : elim;
        cm[i] = __builtin_nontemporal_load(kmask + e);
    }

    // ---- B: tiny prologue loads (same address across all waves; L2-hot) ----
    bf16x8 bfrag[4];
#pragma unroll
    for (int t = 0; t < 4; ++t)
        bfrag[t] = ((const bf16x8*)packB)[t * 64 + lane];
    const f32x4 Sv = ((const f32x4*)SP)[lane];
    const f32x4 Tv = ((const f32x4*)TP)[lane];

    // ---- C: redistribute idx/mask to gather lanes; fold mask -> index ----
    int fid[RB][2];
#pragma unroll
    for (int r = 0; r < RB; ++r) {
#pragma unroll
        for (int kt = 0; kt < 2; ++kt) {
            const int srcl = ((r & 1) << 5) + (kt << 4) + col;
            int idv = __shfl(ci[r >> 1], srcl, 64);
            int mkv = __shfl(cm[r >> 1], srcl, 64);
            idv = idv < 0 ? 0 : idv;
            fid[r][kt] = (mkv == 0) ? idv : N;
        }
    }

    // ---- D: issue ALL 16 gathers ----
    u32x4 g[RB][2];
#pragma unroll
    for (int r = 0; r < RB; ++r)
#pragma unroll
        for (int kt = 0; kt < 2; ++kt)
            g[r][kt] = *(const u32x4*)(tb + (size_t)fid[r][kt] * 32 + c0);

    // ---- E: MFMA + fused BN/ReLU/max + store ----
    const f32x4 zero4 = {0.f, 0.f, 0.f, 0.f};
#pragma unroll
    for (int r = 0; r < RB; ++r) {
        const int m = m0 + r;
        const bf16x8 a0 = __builtin_bit_cast(bf16x8, g[r][0]);
        const bf16x8 a1 = __builtin_bit_cast(bf16x8, g[r][1]);
        float myout = 0.0f;
#pragma unroll
        for (int t = 0; t < 4; ++t) {
            f32x4 d0 = __builtin_amdgcn_mfma_f32_16x16x32_bf16(a0, bfrag[t], zero4, 0, 0, 0);
            f32x4 d1 = __builtin_amdgcn_mfma_f32_16x16x32_bf16(a1, bfrag[t], zero4, 0, 0, 0);
            float v = 0.0f;   // ReLU folded into max
#pragma unroll
            for (int q = 0; q < 4; ++q) {
                v = fmaxf(v, d0[q] * Sv[t] + Tv[t]);
                v = fmaxf(v, d1[q] * Sv[t] + Tv[t]);
            }
            v = fmaxf(v, __shfl_xor(v, 16));
            v = fmaxf(v, __shfl_xor(v, 32));
            if (grp == t) myout = v;
        }
        if (m < M) __builtin_nontemporal_store(myout, out + (size_t)m * 64 + lane);
    }
}

// ---------------- fallback (fp32 gather, no workspace) ----------------
__global__ __launch_bounds__(256, 4) void down_fp32(
    const float* __restrict__ vf, const int* __restrict__ kidx,
    const int* __restrict__ kmask, const float* __restrict__ W,
    const float* __restrict__ bias, const float* __restrict__ gamma,
    const float* __restrict__ beta, const float* __restrict__ mean,
    const float* __restrict__ var, float* __restrict__ out, int M)
{
    const int lane = threadIdx.x & 63;
    const int col  = lane & 15;
    const int grp  = lane >> 4;
    const int c0   = grp << 3;
    const int waves_per_block = blockDim.x >> 6;
    const int wave_id     = blockIdx.x * waves_per_block + (threadIdx.x >> 6);
    const int total_waves = gridDim.x * waves_per_block;

    bf16x8 bfrag[4];
    float S[4], T[4];
#pragma unroll
    for (int t = 0; t < 4; ++t) {
        const int o = t * 16 + col;
        const f32x4 w0 = *(const f32x4*)(W + o * 32 + c0);
        const f32x4 w1 = *(const f32x4*)(W + o * 32 + c0 + 4);
        bf16x8 f;
        f[0]=(__bf16)w0.x; f[1]=(__bf16)w0.y; f[2]=(__bf16)w0.z; f[3]=(__bf16)w0.w;
        f[4]=(__bf16)w1.x; f[5]=(__bf16)w1.y; f[6]=(__bf16)w1.z; f[7]=(__bf16)w1.w;
        bfrag[t] = f;
        const float s = gamma[o] * rsqrtf(var[o] + BN_EPS);
        S[t] = s;
        T[t] = (bias[o] - mean[o]) * s + beta[o];
    }
    const f32x4 zero4 = {0.f, 0.f, 0.f, 0.f};
    for (int m = wave_id; m < M; m += total_waves) {
        const int* idxp = kidx  + (size_t)m * 32;
        const int* mskp = kmask + (size_t)m * 32;
        bf16x8 afrag[2];
#pragma unroll
        for (int kt = 0; kt < 2; ++kt) {
            const int k = kt * 16 + col;
            int id = idxp[k]; id = id < 0 ? 0 : id;
            const float sel = (mskp[k] == 0) ? 1.0f : 0.0f;
            const float* src = vf + (size_t)id * 32 + c0;
            const f32x4 g0 = *(const f32x4*)(src);
            const f32x4 g1 = *(const f32x4*)(src + 4);
            bf16x8 a;
            a[0]=(__bf16)(g0.x*sel); a[1]=(__bf16)(g0.y*sel);
            a[2]=(__bf16)(g0.z*sel); a[3]=(__bf16)(g0.w*sel);
            a[4]=(__bf16)(g1.x*sel); a[5]=(__bf16)(g1.y*sel);
            a[6]=(__bf16)(g1.z*sel); a[7]=(__bf16)(g1.w*sel);
            afrag[kt] = a;
        }
        float myout = 0.0f;
#pragma unroll
        for (int t = 0; t < 4; ++t) {
            f32x4 d0 = __builtin_amdgcn_mfma_f32_16x16x32_bf16(afrag[0], bfrag[t], zero4, 0, 0, 0);
            f32x4 d1 = __builtin_amdgcn_mfma_f32_16x16x32_bf16(afrag[1], bfrag[t], zero4, 0, 0, 0);
            float v = 0.0f;
#pragma unroll
            for (int q = 0; q < 4; ++q) {
                v = fmaxf(v, d0[q] * S[t] + T[t]);
                v = fmaxf(v, d1[q] * S[t] + T[t]);
            }
            v = fmaxf(v, __shfl_xor(v, 16));
            v = fmaxf(v, __shfl_xor(v, 32));
            if (grp == t) myout = v;
        }
        out[(size_t)m * 64 + lane] = myout;
    }
}

extern "C" void kernel_launch(void* const* d_in, const int* in_sizes, int n_in,
                              void* d_out, int out_size, void* d_ws, size_t ws_size,
                              hipStream_t stream) {
    const float* vf    = (const float*)d_in[0];
    const int*   kidx  = (const int*)  d_in[1];
    const int*   kmask = (const int*)  d_in[2];
    const float* W     = (const float*)d_in[3];
    const float* bias  = (const float*)d_in[4];
    const float* gamma = (const float*)d_in[5];
    const float* beta  = (const float*)d_in[6];
    const float* mean  = (const float*)d_in[7];
    const float* var   = (const float*)d_in[8];
    float* out = (float*)d_out;

    const int NC = in_sizes[0];        // N*32 floats
    const int N  = NC / 32;
    const int M  = in_sizes[1] / 32;   // key_indices is [M,32]

    const size_t tbBytes = ((size_t)N + 1) * 32 * sizeof(__bf16);  // 64B-mult
    const size_t packOff = tbBytes;
    const size_t need    = packOff + 4096 + 1024 + 1024;

    if (ws_size >= need) {
        __bf16* tb    = (__bf16*)d_ws;
        u32*    packB = (u32*)  ((char*)d_ws + packOff);
        float*  SP    = (float*)((char*)d_ws + packOff + 4096);
        float*  TP    = (float*)((char*)d_ws + packOff + 4096 + 1024);

        pack_kernel<<<1, 64, 0, stream>>>(W, bias, gamma, beta, mean, var,
                                          tb, packB, SP, TP, N);
        convert_kernel<<<2048, 256, 0, stream>>>(vf, tb, NC / 8);

        const int rows_per_block = (256 / 64) * RB;   // 32
        const int blocks = (M + rows_per_block - 1) / rows_per_block;
        down_bf16<<<blocks, 256, 0, stream>>>(tb, kidx, kmask, packB, SP, TP,
                                              out, M, N);
    } else {
        down_fp32<<<2048, 256, 0, stream>>>(vf, kidx, kmask, W, bias, gamma,
                                            beta, mean, var, out, M);
    }
}